// Round 5
// baseline (291.147 us; speedup 1.0000x reference)
//
#include <hip/hip_runtime.h>
#include <hip/hip_bf16.h>

typedef unsigned short u16;
typedef __attribute__((ext_vector_type(8))) short bf16x8;
typedef __attribute__((ext_vector_type(4))) float f32x4;

// B=1, T=2048, DIM=2048, H=16, KV=4, HD=128
#define T_SEQ 2048
#define DIM   2048
#define NH    16
#define NKV   4
#define HD    128
#define NQKV  3072
#define SCALE 0.08838834764831845f   // 1/sqrt(128), folded into Q at rope
#define NSLOT 61                     // split-K slots per head (chunks of <=5 tiles)

__device__ __forceinline__ u16 f2bf(float f) {
  unsigned int u = __float_as_uint(f);
  unsigned int r = (u + 0x7fffu + ((u >> 16) & 1u)) >> 16;
  return (u16)r;
}
__device__ __forceinline__ float bf2f(u16 v) {
  return __uint_as_float(((unsigned int)v) << 16);
}
// async global->LDS, 16B per lane; LDS dest = wave-uniform base + lane*16
__device__ __forceinline__ void gload_lds16(const u16* g, u16* l) {
  __builtin_amdgcn_global_load_lds(
      (const __attribute__((address_space(1))) unsigned int*)g,
      (__attribute__((address_space(3))) unsigned int*)l, 16, 0, 0);
}

// ---------------- cast fp32 -> bf16: x, wq, wk, wv (wo deferred) ----------
#define C1 1048576
#define C2 2097152
#define C3 2359296
#define C4 2621440
__global__ void cast_main(const float4* __restrict__ x,  const float4* __restrict__ wq,
                          const float4* __restrict__ wk, const float4* __restrict__ wv,
                          ushort4* __restrict__ xb, ushort4* __restrict__ wqkvb) {
  int i = blockIdx.x * 256 + threadIdx.x;
  const float4* src; ushort4* dst; int j;
  if (i < C1)      { src = x;  dst = xb;               j = i; }
  else if (i < C2) { src = wq; dst = wqkvb;            j = i - C1; }
  else if (i < C3) { src = wk; dst = wqkvb + 1048576;  j = i - C2; }
  else             { src = wv; dst = wqkvb + 1310720;  j = i - C3; }
  float4 v = src[j];
  ushort4 o;
  o.x = f2bf(v.x); o.y = f2bf(v.y); o.z = f2bf(v.z); o.w = f2bf(v.w);
  dst[j] = o;
}
__global__ void cast_wo(const float4* __restrict__ wo, ushort4* __restrict__ wob) {
  int i = blockIdx.x * 256 + threadIdx.x;
  float4 v = wo[i];
  ushort4 o;
  o.x = f2bf(v.x); o.y = f2bf(v.y); o.z = f2bf(v.z); o.w = f2bf(v.w);
  wob[i] = o;
}

// ---------------- GEMM (m97-style): C = A @ W^T, bf16 in ------------------
// 128x128 tile, BK=64, global_load_lds width-16 staging, unpadded LDS.
#define BM 128
#define BN 128
#define BK 64

__global__ __launch_bounds__(256) void gemm_bt(
    const u16* __restrict__ A, const u16* __restrict__ W,
    float* __restrict__ Cf, u16* __restrict__ Cb, int M, int N, int K)
{
  __shared__ u16 As[BM * BK];
  __shared__ u16 Bs[BN * BK];
  const int tid  = threadIdx.x;
  const int lane = tid & 63;
  const int wave = tid >> 6;
  const int ln   = lane & 15;
  const int quad = lane >> 4;
  const int m0 = blockIdx.y * BM;
  const int n0 = blockIdx.x * BN;
  const int wm = (wave >> 1) * 64;
  const int wn = (wave & 1) * 64;

  // each wave stages rows [wave*32, wave*32+32): 4 calls x 8 rows (lane L ->
  // row L>>3, col (L&7)*8 -- matches the lane*16B LDS placement exactly)
  const int srow = wave * 32 + (lane >> 3);
  const int scol = (lane & 7) * 8;
  const u16* ga = A + (size_t)(m0 + srow) * K + scol;
  const u16* gw = W + (size_t)(n0 + srow) * K + scol;
  u16* la = &As[wave * 32 * BK];
  u16* lb = &Bs[wave * 32 * BK];

  f32x4 acc[4][4] = {};

  for (int k0 = 0; k0 < K; k0 += BK) {
#pragma unroll
    for (int i = 0; i < 4; ++i) {
      gload_lds16(ga + k0 + (size_t)(i * 8) * K, la + i * 8 * BK);
      gload_lds16(gw + k0 + (size_t)(i * 8) * K, lb + i * 8 * BK);
    }
    __syncthreads();
#pragma unroll
    for (int ks = 0; ks < 2; ++ks) {
      bf16x8 af[4], bfr[4];
#pragma unroll
      for (int mt = 0; mt < 4; ++mt)
        af[mt] = *(const bf16x8*)&As[(wm + mt * 16 + ln) * BK + ks * 32 + quad * 8];
#pragma unroll
      for (int nt = 0; nt < 4; ++nt)
        bfr[nt] = *(const bf16x8*)&Bs[(wn + nt * 16 + ln) * BK + ks * 32 + quad * 8];
#pragma unroll
      for (int mt = 0; mt < 4; ++mt)
#pragma unroll
        for (int nt = 0; nt < 4; ++nt)
          acc[mt][nt] = __builtin_amdgcn_mfma_f32_16x16x32_bf16(
              af[mt], bfr[nt], acc[mt][nt], 0, 0, 0);
    }
    __syncthreads();
  }

#pragma unroll
  for (int mt = 0; mt < 4; ++mt)
#pragma unroll
    for (int nt = 0; nt < 4; ++nt)
#pragma unroll
      for (int r = 0; r < 4; ++r) {
        int row = m0 + wm + mt * 16 + quad * 4 + r;
        int col = n0 + wn + nt * 16 + ln;
        if (Cb) Cb[(size_t)row * N + col] = f2bf(acc[mt][nt][r]);
        else    Cf[(size_t)row * N + col] = acc[mt][nt][r];
      }
}

// ---------------- fused RoPE-Q (scaled) + RoPE-K + V-copy-transpose --------
__global__ void rope_fused(const u16* __restrict__ QKVb,
                           const float* __restrict__ cosT,
                           const float* __restrict__ sinT,
                           u16* __restrict__ Qs, u16* __restrict__ Kb,
                           u16* __restrict__ Vt)
{
  int b = blockIdx.x, d = threadIdx.x;
  if (b < T_SEQ * NH) {                       // RoPE Q, fold SCALE
    int t = b >> 4;
    int h = b & 15;
    const u16* row = QKVb + (size_t)t * NQKV + h * HD;
    float u = bf2f(row[d]);
    float pr = (d < 64) ? -bf2f(row[d + 64]) : bf2f(row[d - 64]);
    float c = cosT[t * HD + d], s = sinT[t * HD + d];
    Qs[(size_t)b * HD + d] = f2bf((u * c + pr * s) * SCALE);
  } else if (b < T_SEQ * (NH + NKV)) {        // RoPE K
    int b2 = b - T_SEQ * NH;
    int t = b2 >> 2;
    int g = b2 & 3;
    const u16* row = QKVb + (size_t)t * NQKV + DIM + g * HD;
    float u = bf2f(row[d]);
    float pr = (d < 64) ? -bf2f(row[d + 64]) : bf2f(row[d - 64]);
    float c = cosT[t * HD + d], s = sinT[t * HD + d];
    Kb[(size_t)b2 * HD + d] = f2bf(u * c + pr * s);
  } else {                                    // V transpose (bf16 copy)
    int b3 = b - T_SEQ * (NH + NKV);
    int idx = b3 * 128 + d;                   // over NKV*HD*T = 2^20
    int t  = idx & (T_SEQ - 1);
    int dd = (idx >> 11) & (HD - 1);
    int g  = idx >> 18;
    Vt[idx] = QKVb[(size_t)t * NQKV + DIM + NKV * HD + g * HD + dd];
  }
}

// ---------------- Flash pass 1: equal-work split-K partials ----------------
// Slots per head: 61 chunks of <=5 key-tiles over the 16 q-tiles (qi): nc(qi)
// = ceil(2(qi+1)/5). srev = 60-blockIdx.x dispatches longest chunks first.
// LDS = 16+16+8 KB = 40960 B exactly -> 4 blocks/CU (full 160 KB).
// XOR swizzle (chunk ^ row&7) keeps every b128 access uniform-8 on banks.
__global__ __launch_bounds__(256) void flash_partial(
    const u16* __restrict__ Qs, const u16* __restrict__ Kb,
    const u16* __restrict__ Vt, u16* __restrict__ Opart,
    float* __restrict__ lpart)
{
  __shared__ u16 Ks[64 * 128];
  __shared__ u16 Vs[128 * 64];
  __shared__ u16 Ps[4][16 * 64];

  const int srev = 60 - (int)blockIdx.x;
  const int h = blockIdx.y;
  int qi, c;
  if      (srev >= 54) { qi = 15; c = srev - 54; }
  else if (srev >= 48) { qi = 14; c = srev - 48; }
  else if (srev >= 42) { qi = 13; c = srev - 42; }
  else if (srev >= 36) { qi = 12; c = srev - 36; }
  else if (srev >= 31) { qi = 11; c = srev - 31; }
  else if (srev >= 26) { qi = 10; c = srev - 26; }
  else if (srev >= 22) { qi = 9;  c = srev - 22; }
  else if (srev >= 18) { qi = 8;  c = srev - 18; }
  else if (srev >= 14) { qi = 7;  c = srev - 14; }
  else if (srev >= 11) { qi = 6;  c = srev - 11; }
  else if (srev >= 8)  { qi = 5;  c = srev - 8; }
  else if (srev >= 6)  { qi = 4;  c = srev - 6; }
  else if (srev >= 4)  { qi = 3;  c = srev - 4; }
  else if (srev >= 2)  { qi = 2;  c = srev - 2; }
  else                 { qi = srev; c = 0; }

  const int nt   = 2 * (qi + 1);
  const int nc   = (2 * qi + 6) / 5;
  const int tb   = nt / nc, rem = nt % nc;
  const int t0   = c * tb + (c < rem ? c : rem);
  const int tcnt = tb + (c < rem ? 1 : 0);
  const int g  = h >> 2;
  const int q0 = qi << 7;

  const int tid  = threadIdx.x;
  const int lane = tid & 63;
  const int w    = tid >> 6;
  const int ln   = lane & 15;
  const int quad = lane >> 4;
  const int lx   = ln & 7;          // swizzle key for reads (row&7 with row=ln)

  // Q A-fragments for this wave's two 16-row m-tiles
  bf16x8 aq[2][4];
#pragma unroll
  for (int mt = 0; mt < 2; ++mt) {
    const u16* qp = Qs + ((size_t)(q0 + w * 32 + mt * 16 + ln) * NH + h) * HD + quad * 8;
#pragma unroll
    for (int ks = 0; ks < 4; ++ks) aq[mt][ks] = *(const bf16x8*)&qp[ks * 32];
  }

  f32x4 o[2][8] = {};
  float rs[2][4] = {};

  for (int it = t0; it < t0 + tcnt; ++it) {
    const int jb = it << 6;
    // stage K tile (64 keys x 128 d), swizzled
    {
      int r = tid >> 4, ch = tid & 15;
#pragma unroll
      for (int i = 0; i < 4; ++i) {
        int row = i * 16 + r;
        *(bf16x8*)&Ks[row * 128 + ((ch ^ (row & 7)) << 3)] =
            *(const bf16x8*)&Kb[((size_t)(jb + row) * NKV + g) * HD + ch * 8];
      }
    }
    // stage V^T tile (128 d x 64 keys), swizzled
    {
      int r = tid >> 3, ch = tid & 7;
#pragma unroll
      for (int i = 0; i < 4; ++i) {
        int row = i * 32 + r;
        *(bf16x8*)&Vs[row * 64 + ((ch ^ (row & 7)) << 3)] =
            *(const bf16x8*)&Vt[(size_t)(g * HD + row) * T_SEQ + jb + ch * 8];
      }
    }
    __syncthreads();

#pragma unroll
    for (int mt = 0; mt < 2; ++mt) {
      const int rbase = q0 + w * 32 + mt * 16 + quad * 4;
      const int rmax  = q0 + w * 32 + mt * 16 + 15;
      if (jb <= rmax) {
        f32x4 sc[4];
#pragma unroll
        for (int nb = 0; nb < 4; ++nb) {
          f32x4 s = {};
#pragma unroll
          for (int ks = 0; ks < 4; ++ks) {
            bf16x8 kf = *(const bf16x8*)&Ks[(nb * 16 + ln) * 128 +
                                            ((((ks << 2) + quad) ^ lx) << 3)];
            s = __builtin_amdgcn_mfma_f32_16x16x32_bf16(aq[mt][ks], kf, s, 0, 0, 0);
          }
          sc[nb] = s;
        }
        const bool diag = (jb >= q0);
#pragma unroll
        for (int nb = 0; nb < 4; ++nb) {
          int j = jb + nb * 16 + ln;
#pragma unroll
          for (int r = 0; r < 4; ++r) {
            float p = (!diag || j <= rbase + r) ? __expf(sc[nb][r]) : 0.f;
            rs[mt][r] += p;
            int prow = quad * 4 + r;
            Ps[w][prow * 64 + ((((nb << 1) + (ln >> 3)) ^ (prow & 7)) << 3) + (ln & 7)] = f2bf(p);
          }
        }
#pragma unroll
        for (int kst = 0; kst < 2; ++kst) {
          bf16x8 ap = *(const bf16x8*)&Ps[w][ln * 64 + ((((kst << 2) + quad) ^ lx) << 3)];
#pragma unroll
          for (int nb8 = 0; nb8 < 8; ++nb8) {
            bf16x8 bv = *(const bf16x8*)&Vs[(nb8 * 16 + ln) * 64 +
                                            ((((kst << 2) + quad) ^ lx) << 3)];
            o[mt][nb8] = __builtin_amdgcn_mfma_f32_16x16x32_bf16(ap, bv, o[mt][nb8], 0, 0, 0);
          }
        }
      }
    }
    __syncthreads();
  }

  // epilogue: write O partial (bf16) + row-sum partial (fp32)
  const int slot = h * NSLOT + srev;
  u16*   op = Opart + (size_t)slot * (128 * 128);
  float* lp = lpart + (size_t)slot * 128;
#pragma unroll
  for (int mt = 0; mt < 2; ++mt) {
#pragma unroll
    for (int r = 0; r < 4; ++r)
#pragma unroll
      for (int off = 1; off < 16; off <<= 1)
        rs[mt][r] += __shfl_xor(rs[mt][r], off);
    int rowb = w * 32 + mt * 16 + quad * 4;
#pragma unroll
    for (int r = 0; r < 4; ++r) {
#pragma unroll
      for (int nb8 = 0; nb8 < 8; ++nb8)
        op[(rowb + r) * 128 + nb8 * 16 + ln] = f2bf(o[mt][nb8][r]);
      if (ln == 0) lp[rowb + r] = rs[mt][r];
    }
  }
}

// ---------------- Flash pass 2: reduce chunks + normalize ------------------
// grid (T/2, NH), block 256 (2 rows x 128 dims)
__global__ void flash_reduce(const u16* __restrict__ Opart,
                             const float* __restrict__ lpart,
                             u16* __restrict__ AO)
{
  const int h = blockIdx.y;
  const int d = threadIdx.x & 127;
  const int t = blockIdx.x * 2 + (threadIdx.x >> 7);
  const int qi = t >> 7, r = t & 127;
  int p = 0;
#pragma unroll
  for (int j = 0; j < 16; ++j) p += (j < qi) ? ((2 * j + 6) / 5) : 0;
  const int nc = (2 * qi + 6) / 5;
  const int base = h * NSLOT + p;
  float so = 0.f, sl = 0.f;
  for (int cc = 0; cc < nc; ++cc) {
    so += bf2f(Opart[(size_t)(base + cc) * (128 * 128) + r * 128 + d]);
    sl += lpart[(size_t)(base + cc) * 128 + r];
  }
  AO[(size_t)t * DIM + h * HD + d] = f2bf(so / sl);
}

// ---------------- launch ----------------
// Workspace (peak 51.5 MB):
//   [ 0, 8)  xb       (dead after gemmQKV) -> wob (cast_wo)
//   [ 8,20)  wqkvb    (dead after gemmQKV) -> Qs[8,16) Kb[16,18) Vt[18,20)
//                     Qs/Kb/Vt dead after flash_partial -> AO at [8,16)
//   [20,32)  QKVb     (dead after rope)    -> Opart [20, 50.5)
//   [51, 51.5) lpart
extern "C" void kernel_launch(void* const* d_in, const int* in_sizes, int n_in,
                              void* d_out, int out_size, void* d_ws, size_t ws_size,
                              hipStream_t stream) {
  const float* x    = (const float*)d_in[0];
  const float* wq   = (const float*)d_in[1];
  const float* wk   = (const float*)d_in[2];
  const float* wv   = (const float*)d_in[3];
  const float* wo   = (const float*)d_in[4];
  const float* cosT = (const float*)d_in[5];
  const float* sinT = (const float*)d_in[6];
  float* out = (float*)d_out;

  char* ws = (char*)d_ws;
  const size_t MB = 1024 * 1024;
  u16*   xb    = (u16*)(ws + 0 * MB);
  u16*   wqkvb = (u16*)(ws + 8 * MB);
  u16*   QKVb  = (u16*)(ws + 20 * MB);
  u16*   wob   = (u16*)(ws + 0 * MB);    // overlays xb (dead after gemmQKV)
  u16*   Qs    = (u16*)(ws + 8 * MB);    // overlays wqkvb (dead)
  u16*   Kb    = (u16*)(ws + 16 * MB);
  u16*   Vt    = (u16*)(ws + 18 * MB);
  u16*   Opart = (u16*)(ws + 20 * MB);   // overlays QKVb (dead after rope)
  float* lpart = (float*)(ws + 51 * MB);
  u16*   AO    = (u16*)(ws + 8 * MB);    // overlays Qs (dead after flash)

  // 1. cast x + qkv weights
  cast_main<<<C4 / 256, 256, 0, stream>>>(
      (const float4*)x, (const float4*)wq, (const float4*)wk, (const float4*)wv,
      (ushort4*)xb, (ushort4*)wqkvb);

  // 2. fused QKV projection (bf16 out)
  gemm_bt<<<dim3(NQKV / BN, T_SEQ / BM), 256, 0, stream>>>(
      xb, wqkvb, nullptr, QKVb, T_SEQ, NQKV, DIM);

  // 3. cast wo (xb region now dead)
  cast_wo<<<(DIM * DIM / 4) / 256, 256, 0, stream>>>((const float4*)wo, (ushort4*)wob);

  // 4. fused RoPE-Q(+scale) / RoPE-K / V-transpose
  rope_fused<<<T_SEQ * (NH + NKV) + (NKV * HD * T_SEQ) / 128, HD, 0, stream>>>(
      QKVb, cosT, sinT, Qs, Kb, Vt);

  // 5. flash attention: 976 equal-work split-K blocks, longest first
  flash_partial<<<dim3(NSLOT, NH), 256, 0, stream>>>(Qs, Kb, Vt, Opart, lpart);
  flash_reduce<<<dim3(T_SEQ / 2, NH), 256, 0, stream>>>(Opart, lpart, AO);

  // 6. output projection, fp32 out
  gemm_bt<<<dim3(DIM / BN, T_SEQ / BM), 256, 0, stream>>>(
      AO, wob, out, nullptr, T_SEQ, DIM, DIM);
}

// Round 6
// 288.212 us; speedup vs baseline: 1.0102x; 1.0102x over previous
//
#include <hip/hip_runtime.h>
#include <hip/hip_bf16.h>

typedef unsigned short u16;
typedef __attribute__((ext_vector_type(8))) short bf16x8;
typedef __attribute__((ext_vector_type(4))) float f32x4;

// B=1, T=2048, DIM=2048, H=16, KV=4, HD=128
#define T_SEQ 2048
#define DIM   2048
#define NH    16
#define NKV   4
#define HD    128
#define NQKV  3072
#define SCALE 0.08838834764831845f   // 1/sqrt(128), folded into Q at rope
#define NSLOT 61                     // flash split-K slots per head

__device__ __forceinline__ u16 f2bf(float f) {
  unsigned int u = __float_as_uint(f);
  unsigned int r = (u + 0x7fffu + ((u >> 16) & 1u)) >> 16;
  return (u16)r;
}
__device__ __forceinline__ float bf2f(u16 v) {
  return __uint_as_float(((unsigned int)v) << 16);
}
// async global->LDS, 16B per lane; LDS dest = wave-uniform base + lane*16
__device__ __forceinline__ void gload_lds16(const u16* g, u16* l) {
  __builtin_amdgcn_global_load_lds(
      (const __attribute__((address_space(1))) unsigned int*)g,
      (__attribute__((address_space(3))) unsigned int*)l, 16, 0, 0);
}

// ---------------- cast fp32 -> bf16: x, wq, wk, wv (wo deferred) ----------
#define C1 1048576
#define C2 2097152
#define C3 2359296
#define C4 2621440
__global__ void cast_main(const float4* __restrict__ x,  const float4* __restrict__ wq,
                          const float4* __restrict__ wk, const float4* __restrict__ wv,
                          ushort4* __restrict__ xb, ushort4* __restrict__ wqkvb) {
  int i = blockIdx.x * 256 + threadIdx.x;
  const float4* src; ushort4* dst; int j;
  if (i < C1)      { src = x;  dst = xb;               j = i; }
  else if (i < C2) { src = wq; dst = wqkvb;            j = i - C1; }
  else if (i < C3) { src = wk; dst = wqkvb + 1048576;  j = i - C2; }
  else             { src = wv; dst = wqkvb + 1310720;  j = i - C3; }
  float4 v = src[j];
  ushort4 o;
  o.x = f2bf(v.x); o.y = f2bf(v.y); o.z = f2bf(v.z); o.w = f2bf(v.w);
  dst[j] = o;
}
__global__ void cast_wo(const float4* __restrict__ wo, ushort4* __restrict__ wob) {
  int i = blockIdx.x * 256 + threadIdx.x;
  float4 v = wo[i];
  ushort4 o;
  o.x = f2bf(v.x); o.y = f2bf(v.y); o.z = f2bf(v.z); o.w = f2bf(v.w);
  wob[i] = o;
}

// ---------------- GEMM (m97-style, split-K over gridDim.z) -----------------
// C_z(M,N) = A(M, z*Krun : (z+1)*Krun) @ W^T slice; partials bf16 to Cb+z*M*N
// 128x128 tile, BK=64, global_load_lds width-16 staging, unpadded LDS.
#define BM 128
#define BN 128
#define BK 64

__global__ __launch_bounds__(256) void gemm_bt(
    const u16* __restrict__ A, const u16* __restrict__ W,
    float* __restrict__ Cf, u16* __restrict__ Cb,
    int M, int N, int Kstride, int Krun)
{
  __shared__ u16 As[BM * BK];
  __shared__ u16 Bs[BN * BK];
  const int tid  = threadIdx.x;
  const int lane = tid & 63;
  const int wave = tid >> 6;
  const int ln   = lane & 15;
  const int quad = lane >> 4;
  const int m0 = blockIdx.y * BM;
  const int n0 = blockIdx.x * BN;
  const int koff = blockIdx.z * Krun;
  const int wm = (wave >> 1) * 64;
  const int wn = (wave & 1) * 64;

  // each wave stages rows [wave*32, wave*32+32): 4 calls x 8 rows
  const int srow = wave * 32 + (lane >> 3);
  const int scol = (lane & 7) * 8;
  const u16* ga = A + (size_t)(m0 + srow) * Kstride + koff + scol;
  const u16* gw = W + (size_t)(n0 + srow) * Kstride + koff + scol;
  u16* la = &As[wave * 32 * BK];
  u16* lb = &Bs[wave * 32 * BK];

  f32x4 acc[4][4] = {};

  for (int k0 = 0; k0 < Krun; k0 += BK) {
#pragma unroll
    for (int i = 0; i < 4; ++i) {
      gload_lds16(ga + k0 + (size_t)(i * 8) * Kstride, la + i * 8 * BK);
      gload_lds16(gw + k0 + (size_t)(i * 8) * Kstride, lb + i * 8 * BK);
    }
    __syncthreads();
#pragma unroll
    for (int ks = 0; ks < 2; ++ks) {
      bf16x8 af[4], bfr[4];
#pragma unroll
      for (int mt = 0; mt < 4; ++mt)
        af[mt] = *(const bf16x8*)&As[(wm + mt * 16 + ln) * BK + ks * 32 + quad * 8];
#pragma unroll
      for (int nt = 0; nt < 4; ++nt)
        bfr[nt] = *(const bf16x8*)&Bs[(wn + nt * 16 + ln) * BK + ks * 32 + quad * 8];
#pragma unroll
      for (int mt = 0; mt < 4; ++mt)
#pragma unroll
        for (int nt = 0; nt < 4; ++nt)
          acc[mt][nt] = __builtin_amdgcn_mfma_f32_16x16x32_bf16(
              af[mt], bfr[nt], acc[mt][nt], 0, 0, 0);
    }
    __syncthreads();
  }

  const size_t zoff = (size_t)blockIdx.z * M * N;
#pragma unroll
  for (int mt = 0; mt < 4; ++mt)
#pragma unroll
    for (int nt = 0; nt < 4; ++nt)
#pragma unroll
      for (int r = 0; r < 4; ++r) {
        int row = m0 + wm + mt * 16 + quad * 4 + r;
        int col = n0 + wn + nt * 16 + ln;
        if (Cb) Cb[zoff + (size_t)row * N + col] = f2bf(acc[mt][nt][r]);
        else    Cf[zoff + (size_t)row * N + col] = acc[mt][nt][r];
      }
}

// ------- fused QKV split-K reduce + RoPE-Q(+scale) + RoPE-K + V-transpose --
// QKVp: two bf16 partials of (T, 3072), second at +T*NQKV elements.
__global__ void rope_fused(const u16* __restrict__ QKVp,
                           const float* __restrict__ cosT,
                           const float* __restrict__ sinT,
                           u16* __restrict__ Qs, u16* __restrict__ Kb,
                           u16* __restrict__ Vt)
{
  const u16* p0 = QKVp;
  const u16* p1 = QKVp + (size_t)T_SEQ * NQKV;
  int b = blockIdx.x, d = threadIdx.x;
  if (b < T_SEQ * NH) {                       // RoPE Q, fold SCALE
    int t = b >> 4;
    int h = b & 15;
    size_t base = (size_t)t * NQKV + h * HD;
    float u = bf2f(p0[base + d]) + bf2f(p1[base + d]);
    int dr = (d < 64) ? d + 64 : d - 64;
    float pr = bf2f(p0[base + dr]) + bf2f(p1[base + dr]);
    if (d < 64) pr = -pr;
    float c = cosT[t * HD + d], s = sinT[t * HD + d];
    Qs[(size_t)b * HD + d] = f2bf((u * c + pr * s) * SCALE);
  } else if (b < T_SEQ * (NH + NKV)) {        // RoPE K
    int b2 = b - T_SEQ * NH;
    int t = b2 >> 2;
    int g = b2 & 3;
    size_t base = (size_t)t * NQKV + DIM + g * HD;
    float u = bf2f(p0[base + d]) + bf2f(p1[base + d]);
    int dr = (d < 64) ? d + 64 : d - 64;
    float pr = bf2f(p0[base + dr]) + bf2f(p1[base + dr]);
    if (d < 64) pr = -pr;
    float c = cosT[t * HD + d], s = sinT[t * HD + d];
    Kb[(size_t)b2 * HD + d] = f2bf(u * c + pr * s);
  } else {                                    // V reduce + transpose
    int b3 = b - T_SEQ * (NH + NKV);
    int idx = b3 * 128 + d;                   // over NKV*HD*T = 2^20
    int t  = idx & (T_SEQ - 1);
    int dd = (idx >> 11) & (HD - 1);
    int g  = idx >> 18;
    size_t src = (size_t)t * NQKV + DIM + NKV * HD + g * HD + dd;
    Vt[idx] = f2bf(bf2f(p0[src]) + bf2f(p1[src]));
  }
}

// ---------------- Flash pass 1: equal-work split-K partials ----------------
// (unchanged from R5: 61 slots/head, chunks <=5 tiles, longest first,
//  LDS 40 KB exactly -> 4 blocks/CU, XOR-swizzled tiles)
__global__ __launch_bounds__(256) void flash_partial(
    const u16* __restrict__ Qs, const u16* __restrict__ Kb,
    const u16* __restrict__ Vt, u16* __restrict__ Opart,
    float* __restrict__ lpart)
{
  __shared__ u16 Ks[64 * 128];
  __shared__ u16 Vs[128 * 64];
  __shared__ u16 Ps[4][16 * 64];

  const int srev = 60 - (int)blockIdx.x;
  const int h = blockIdx.y;
  int qi, c;
  if      (srev >= 54) { qi = 15; c = srev - 54; }
  else if (srev >= 48) { qi = 14; c = srev - 48; }
  else if (srev >= 42) { qi = 13; c = srev - 42; }
  else if (srev >= 36) { qi = 12; c = srev - 36; }
  else if (srev >= 31) { qi = 11; c = srev - 31; }
  else if (srev >= 26) { qi = 10; c = srev - 26; }
  else if (srev >= 22) { qi = 9;  c = srev - 22; }
  else if (srev >= 18) { qi = 8;  c = srev - 18; }
  else if (srev >= 14) { qi = 7;  c = srev - 14; }
  else if (srev >= 11) { qi = 6;  c = srev - 11; }
  else if (srev >= 8)  { qi = 5;  c = srev - 8; }
  else if (srev >= 6)  { qi = 4;  c = srev - 6; }
  else if (srev >= 4)  { qi = 3;  c = srev - 4; }
  else if (srev >= 2)  { qi = 2;  c = srev - 2; }
  else                 { qi = srev; c = 0; }

  const int nt   = 2 * (qi + 1);
  const int nc   = (2 * qi + 6) / 5;
  const int tb   = nt / nc, rem = nt % nc;
  const int t0   = c * tb + (c < rem ? c : rem);
  const int tcnt = tb + (c < rem ? 1 : 0);
  const int g  = h >> 2;
  const int q0 = qi << 7;

  const int tid  = threadIdx.x;
  const int lane = tid & 63;
  const int w    = tid >> 6;
  const int ln   = lane & 15;
  const int quad = lane >> 4;
  const int lx   = ln & 7;

  bf16x8 aq[2][4];
#pragma unroll
  for (int mt = 0; mt < 2; ++mt) {
    const u16* qp = Qs + ((size_t)(q0 + w * 32 + mt * 16 + ln) * NH + h) * HD + quad * 8;
#pragma unroll
    for (int ks = 0; ks < 4; ++ks) aq[mt][ks] = *(const bf16x8*)&qp[ks * 32];
  }

  f32x4 o[2][8] = {};
  float rs[2][4] = {};

  for (int it = t0; it < t0 + tcnt; ++it) {
    const int jb = it << 6;
    {
      int r = tid >> 4, ch = tid & 15;
#pragma unroll
      for (int i = 0; i < 4; ++i) {
        int row = i * 16 + r;
        *(bf16x8*)&Ks[row * 128 + ((ch ^ (row & 7)) << 3)] =
            *(const bf16x8*)&Kb[((size_t)(jb + row) * NKV + g) * HD + ch * 8];
      }
    }
    {
      int r = tid >> 3, ch = tid & 7;
#pragma unroll
      for (int i = 0; i < 4; ++i) {
        int row = i * 32 + r;
        *(bf16x8*)&Vs[row * 64 + ((ch ^ (row & 7)) << 3)] =
            *(const bf16x8*)&Vt[(size_t)(g * HD + row) * T_SEQ + jb + ch * 8];
      }
    }
    __syncthreads();

#pragma unroll
    for (int mt = 0; mt < 2; ++mt) {
      const int rbase = q0 + w * 32 + mt * 16 + quad * 4;
      const int rmax  = q0 + w * 32 + mt * 16 + 15;
      if (jb <= rmax) {
        f32x4 sc[4];
#pragma unroll
        for (int nb = 0; nb < 4; ++nb) {
          f32x4 s = {};
#pragma unroll
          for (int ks = 0; ks < 4; ++ks) {
            bf16x8 kf = *(const bf16x8*)&Ks[(nb * 16 + ln) * 128 +
                                            ((((ks << 2) + quad) ^ lx) << 3)];
            s = __builtin_amdgcn_mfma_f32_16x16x32_bf16(aq[mt][ks], kf, s, 0, 0, 0);
          }
          sc[nb] = s;
        }
        const bool diag = (jb >= q0);
#pragma unroll
        for (int nb = 0; nb < 4; ++nb) {
          int j = jb + nb * 16 + ln;
#pragma unroll
          for (int r = 0; r < 4; ++r) {
            float p = (!diag || j <= rbase + r) ? __expf(sc[nb][r]) : 0.f;
            rs[mt][r] += p;
            int prow = quad * 4 + r;
            Ps[w][prow * 64 + ((((nb << 1) + (ln >> 3)) ^ (prow & 7)) << 3) + (ln & 7)] = f2bf(p);
          }
        }
#pragma unroll
        for (int kst = 0; kst < 2; ++kst) {
          bf16x8 ap = *(const bf16x8*)&Ps[w][ln * 64 + ((((kst << 2) + quad) ^ lx) << 3)];
#pragma unroll
          for (int nb8 = 0; nb8 < 8; ++nb8) {
            bf16x8 bv = *(const bf16x8*)&Vs[(nb8 * 16 + ln) * 64 +
                                            ((((kst << 2) + quad) ^ lx) << 3)];
            o[mt][nb8] = __builtin_amdgcn_mfma_f32_16x16x32_bf16(ap, bv, o[mt][nb8], 0, 0, 0);
          }
        }
      }
    }
    __syncthreads();
  }

  const int slot = h * NSLOT + srev;
  u16*   op = Opart + (size_t)slot * (128 * 128);
  float* lp = lpart + (size_t)slot * 128;
#pragma unroll
  for (int mt = 0; mt < 2; ++mt) {
#pragma unroll
    for (int r = 0; r < 4; ++r)
#pragma unroll
      for (int off = 1; off < 16; off <<= 1)
        rs[mt][r] += __shfl_xor(rs[mt][r], off);
    int rowb = w * 32 + mt * 16 + quad * 4;
#pragma unroll
    for (int r = 0; r < 4; ++r) {
#pragma unroll
      for (int nb8 = 0; nb8 < 8; ++nb8)
        op[(rowb + r) * 128 + nb8 * 16 + ln] = f2bf(o[mt][nb8][r]);
      if (ln == 0) lp[rowb + r] = rs[mt][r];
    }
  }
}

// ---------------- Flash pass 2: reduce chunks + normalize ------------------
__global__ void flash_reduce(const u16* __restrict__ Opart,
                             const float* __restrict__ lpart,
                             u16* __restrict__ AO)
{
  const int h = blockIdx.y;
  const int d = threadIdx.x & 127;
  const int t = blockIdx.x * 2 + (threadIdx.x >> 7);
  const int qi = t >> 7, r = t & 127;
  int p = 0;
#pragma unroll
  for (int j = 0; j < 16; ++j) p += (j < qi) ? ((2 * j + 6) / 5) : 0;
  const int nc = (2 * qi + 6) / 5;
  const int base = h * NSLOT + p;
  float so = 0.f, sl = 0.f;
  for (int cc = 0; cc < nc; ++cc) {
    so += bf2f(Opart[(size_t)(base + cc) * (128 * 128) + r * 128 + d]);
    sl += lpart[(size_t)(base + cc) * 128 + r];
  }
  AO[(size_t)t * DIM + h * HD + d] = f2bf(so / sl);
}

// ---------------- out-proj split-K reduce: fp32 out ------------------------
__global__ void reduce_out(const ushort4* __restrict__ p0,
                           const ushort4* __restrict__ p1,
                           float4* __restrict__ out)
{
  int i = blockIdx.x * 256 + threadIdx.x;   // over M*N/4 = 1048576
  ushort4 a = p0[i], b = p1[i];
  float4 v;
  v.x = bf2f(a.x) + bf2f(b.x);
  v.y = bf2f(a.y) + bf2f(b.y);
  v.z = bf2f(a.z) + bf2f(b.z);
  v.w = bf2f(a.w) + bf2f(b.w);
  out[i] = v;
}

// ---------------- launch ----------------
// Workspace (peak 51.5 MB):
//   [ 0, 8)   xb        (dead after QKV gemm) -> Qs
//   [ 8,20)   wqkvb     (dead after QKV gemm) -> Kb[8,10) Vt[10,12) wob[12,20)
//   [20,44)   QKVp x2   (dead after rope)     -> Opart[20,50.5) -> OPp[20,36)
//   [51,51.5) lpart
//   AO at [0,8) after flash (Qs dead post-flash_partial)
extern "C" void kernel_launch(void* const* d_in, const int* in_sizes, int n_in,
                              void* d_out, int out_size, void* d_ws, size_t ws_size,
                              hipStream_t stream) {
  const float* x    = (const float*)d_in[0];
  const float* wq   = (const float*)d_in[1];
  const float* wk   = (const float*)d_in[2];
  const float* wv   = (const float*)d_in[3];
  const float* wo   = (const float*)d_in[4];
  const float* cosT = (const float*)d_in[5];
  const float* sinT = (const float*)d_in[6];
  float* out = (float*)d_out;

  char* ws = (char*)d_ws;
  const size_t MB = 1024 * 1024;
  u16*   xb    = (u16*)(ws + 0 * MB);
  u16*   wqkvb = (u16*)(ws + 8 * MB);
  u16*   QKVp  = (u16*)(ws + 20 * MB);   // 2 x 12 MiB bf16 partials
  u16*   Qs    = (u16*)(ws + 0 * MB);    // overlays xb (dead after QKV gemm)
  u16*   Kb    = (u16*)(ws + 8 * MB);
  u16*   Vt    = (u16*)(ws + 10 * MB);
  u16*   wob   = (u16*)(ws + 12 * MB);
  u16*   Opart = (u16*)(ws + 20 * MB);   // overlays QKVp (dead after rope)
  float* lpart = (float*)(ws + 51 * MB);
  u16*   AO    = (u16*)(ws + 0 * MB);    // overlays Qs (dead after flash)
  u16*   OPp   = (u16*)(ws + 20 * MB);   // 2 x 8 MiB (Opart dead after reduce)

  // 1. cast x + qkv weights
  cast_main<<<C4 / 256, 256, 0, stream>>>(
      (const float4*)x, (const float4*)wq, (const float4*)wk, (const float4*)wv,
      (ushort4*)xb, (ushort4*)wqkvb);

  // 2. fused QKV projection, split-K=2 (768 blocks), bf16 partials
  gemm_bt<<<dim3(NQKV / BN, T_SEQ / BM, 2), 256, 0, stream>>>(
      xb, wqkvb, nullptr, QKVp, T_SEQ, NQKV, DIM, DIM / 2);

  // 3. cast wo into dead wqkvb region
  cast_wo<<<(DIM * DIM / 4) / 256, 256, 0, stream>>>((const float4*)wo, (ushort4*)wob);

  // 4. fused QKV-reduce + RoPE-Q(+scale) / RoPE-K / V-transpose
  rope_fused<<<T_SEQ * (NH + NKV) + (NKV * HD * T_SEQ) / 128, HD, 0, stream>>>(
      QKVp, cosT, sinT, Qs, Kb, Vt);

  // 5. flash attention: 976 equal-work split-K blocks, longest first
  flash_partial<<<dim3(NSLOT, NH), 256, 0, stream>>>(Qs, Kb, Vt, Opart, lpart);
  flash_reduce<<<dim3(T_SEQ / 2, NH), 256, 0, stream>>>(Opart, lpart, AO);

  // 6. output projection, split-K=2 (512 blocks), bf16 partials + reduce
  gemm_bt<<<dim3(DIM / BN, T_SEQ / BM, 2), 256, 0, stream>>>(
      AO, wob, nullptr, OPp, T_SEQ, DIM, DIM, DIM / 2);
  reduce_out<<<(DIM * DIM / 4) / 256, 256, 0, stream>>>(
      (const ushort4*)OPp, (const ushort4*)OPp + (size_t)T_SEQ * DIM / 4, (float4*)out);
}